// Round 1
// 601.807 us; speedup vs baseline: 1.0248x; 1.0248x over previous
//
#include <hip/hip_runtime.h>

#define BB  256
#define TT  500
#define ENC 700
#define ENC_PAD 704   // rows 700..703 of w1t are zeros (gather padding target)
#define HID 128

// ---------------------------------------------------------------------------
// Kernel 1: transpose w1 (HID, ENC) -> w1t (ENC_PAD, HID); pad rows = 0
// ---------------------------------------------------------------------------
__global__ __launch_bounds__(128) void transpose_w1_kernel(const float* __restrict__ w1,
                                                           float* __restrict__ w1t) {
    int c = blockIdx.x;      // 0..ENC_PAD-1
    int h = threadIdx.x;     // 0..HID-1
    w1t[c * HID + h] = (c < ENC) ? w1[h * ENC + c] : 0.0f;
}

// ---------------------------------------------------------------------------
// Kernel 2 (v4): compress + gather sparse binary GEMM, bit-exact sum order.
//   Two rows per wave. Phase 1/2 build per-row ascending column lists via
//   ballot-compact (full wave per row). Phase 3: half-wave float4 gather —
//   lanes 0..31 own row A channels 4l..4l+3, lanes 32..63 own row B.
//   Explicit 2-stage software pipeline keeps 8 x 1 KB loads in flight per
//   wave (the previous version compiled to VGPR=28 and serialized the
//   gather ~2 loads deep -> latency-bound at 27% VALUBusy / 1.1 TB/s).
//   Per-channel accumulation is a SINGLE ordered chain in ascending column
//   order -> bit-identical to the reference sum (pads add exact +0.0).
// ---------------------------------------------------------------------------
__global__ __launch_bounds__(256, 4) void spmm4_kernel(const float* __restrict__ x,
                                                       const float* __restrict__ w1t,
                                                       float* __restrict__ h) {
    __shared__ ushort lists[8][152];                  // wave-private pairs of lists
    const int lane = threadIdx.x & 63;
    const int w = threadIdx.x >> 6;
    const int rbase = blockIdx.x * 8 + w * 2;         // rows rbase, rbase+1 (row = b*TT + t)
    const unsigned long long lt = (1ull << lane) - 1ull;

    // ---- phase 1: load both rows, all 22 dwords issued together ----
    const float* xrowA = x + (size_t)rbase * ENC;
    const float* xrowB = xrowA + ENC;
    float xva[11], xvb[11];
    #pragma unroll
    for (int k = 0; k < 11; ++k) {
        int c = k * 64 + lane;
        xva[k] = (c < ENC) ? xrowA[c] : 0.0f;
    }
    #pragma unroll
    for (int k = 0; k < 11; ++k) {
        int c = k * 64 + lane;
        xvb[k] = (c < ENC) ? xrowB[c] : 0.0f;
    }

    // ---- phase 2: ballot-compact into strictly ascending column lists ----
    int nA = 0, nB = 0;
    #pragma unroll
    for (int k = 0; k < 11; ++k) {
        bool act = (xva[k] != 0.0f);
        unsigned long long m = __ballot(act);
        if (act) {
            int pos = nA + (int)__popcll(m & lt);
            if (pos < 144) lists[2 * w + 0][pos] = (ushort)(k * 64 + lane);
        }
        nA += (int)__popcll(m);
    }
    #pragma unroll
    for (int k = 0; k < 11; ++k) {
        bool act = (xvb[k] != 0.0f);
        unsigned long long m = __ballot(act);
        if (act) {
            int pos = nB + (int)__popcll(m & lt);
            if (pos < 144) lists[2 * w + 1][pos] = (ushort)(k * 64 + lane);
        }
        nB += (int)__popcll(m);
    }
    nA = (nA < 144) ? nA : 144;                       // statistically never truncates
    nB = (nB < 144) ? nB : 144;
    int npmax = ((nA > nB ? nA : nB) + 3) & ~3;       // shared trip count, x4
    if (npmax < 4) npmax = 4;
    // pad both lists up to npmax+4 (pipeline overrun reads) with zero column
    for (int p = nA + lane; p < npmax + 4; p += 64) lists[2 * w + 0][p] = (ushort)ENC;
    for (int p = nB + lane; p < npmax + 4; p += 64) lists[2 * w + 1][p] = (ushort)ENC;
    // no __syncthreads needed: lists are wave-private; in-wave LDS RAW is
    // ordered by the compiler's lgkmcnt waits.

    // ---- phase 3: half-wave float4 gather, 2-stage pipeline ----
    const int half = lane >> 5;                       // 0 -> row A, 1 -> row B
    const int hl = lane & 31;                         // channel group: 4*hl..4*hl+3
    const ushort* mylist = lists[2 * w + half];
    const float* wb = w1t + 4 * hl;

    float a0 = 0.f, a1 = 0.f, a2 = 0.f, a3 = 0.f;

    int c0 = mylist[0], c1 = mylist[1], c2 = mylist[2], c3 = mylist[3];
    float4 p0 = *(const float4*)(wb + (size_t)c0 * HID);
    float4 p1 = *(const float4*)(wb + (size_t)c1 * HID);
    float4 p2 = *(const float4*)(wb + (size_t)c2 * HID);
    float4 p3 = *(const float4*)(wb + (size_t)c3 * HID);

    for (int j = 0; j < npmax; j += 4) {
        // issue next stage first: 8 KB in flight per wave
        int d0 = mylist[j + 4], d1 = mylist[j + 5];
        int d2 = mylist[j + 6], d3 = mylist[j + 7];
        float4 q0 = *(const float4*)(wb + (size_t)d0 * HID);
        float4 q1 = *(const float4*)(wb + (size_t)d1 * HID);
        float4 q2 = *(const float4*)(wb + (size_t)d2 * HID);
        float4 q3 = *(const float4*)(wb + (size_t)d3 * HID);
        // ordered ascending-column accumulation; 4 independent channel chains
        a0 += p0.x; a1 += p0.y; a2 += p0.z; a3 += p0.w;
        a0 += p1.x; a1 += p1.y; a2 += p1.z; a3 += p1.w;
        a0 += p2.x; a1 += p2.y; a2 += p2.z; a3 += p2.w;
        a0 += p3.x; a1 += p3.y; a2 += p3.z; a3 += p3.w;
        p0 = q0; p1 = q1; p2 = q2; p3 = q3;
    }

    const int r = rbase + half;
    const int b = r / TT;
    const int t = r - b * TT;
    float4* dst = (float4*)(h + (size_t)t * (BB * HID) + (size_t)b * HID) + hl;
    *dst = make_float4(a0, a1, a2, a3);
}

// ---------------------------------------------------------------------------
// async global->LDS copy, 4 B per lane (wave-uniform LDS base + lane*4)
// ---------------------------------------------------------------------------
__device__ __forceinline__ void async_copy4(const float* g, float* l) {
    __builtin_amdgcn_global_load_lds(
        (const __attribute__((address_space(1))) void*)g,
        (__attribute__((address_space(3))) void*)l,
        4, 0, 0);
}

// ---------------------------------------------------------------------------
// Kernel 3: temporal pipeline per b. Block = 128 threads (2 waves),
// 1 channel/lane. h staged through double-buffered LDS chunks of 50 t
// via async global_load_lds issued one chunk ahead.
// ---------------------------------------------------------------------------
__global__ __launch_bounds__(128) void recur_kernel(const float* __restrict__ hgl,
                                                    const float* __restrict__ w2,
                                                    float* __restrict__ out) {
    __shared__ float hbuf[2][50 * 128];   // 51.2 KB
    __shared__ float vbuf[50 * 129];      // 25.8 KB, stride 129 -> conflict-free rows
    __shared__ float pbuf[2][50];

    const int b = blockIdx.x;
    const int tid = threadIdx.x;          // 0..127
    const int lane = tid & 63;
    const int w = tid >> 6;

    const float D   = 0.95122942450071400910f;                                 // exp(-1/20)
    const float CD  = (float)(0.13591409142295226 * 0.95122942450071400910);   // (e/20)*d
    const float CRD = (float)(-0.27182818284590452 * 0.95122942450071400910);  // (-2e/20)*d

    float ap = 0.f, aq = 0.f, rp = 0.f, rq = 0.f;   // layer-1, channel = tid
    float Ap = 0.f, Aq = 0.f, Rp = 0.f, Rq = 0.f;   // layer-2, redundant on all lanes
    const float w2v = w2[tid];

    // stage chunk -> hbuf[buf]: wave w loads rows w*25..w*25+24, 2 halves each
    auto stage = [&](int chunk, int buf) {
        const int t0 = chunk * 50 + w * 25;
        #pragma unroll 5
        for (int i = 0; i < 25; ++i) {
            const float* g = hgl + (size_t)(t0 + i) * (BB * HID) + (size_t)b * HID + lane;
            float* l = &hbuf[buf][(w * 25 + i) * 128];
            async_copy4(g, l);
            async_copy4(g + 64, l + 64);
        }
    };

    stage(0, 0);
    __syncthreads();   // drains vmcnt -> chunk 0 resident

    for (int chunk = 0; chunk < 10; ++chunk) {
        const int cur = chunk & 1;
        if (chunk < 9) stage(chunk + 1, cur ^ 1);   // async, drained at next barrier

        // ---- layer-1 scan, 50 steps ----
        const float* hb = &hbuf[cur][0];
        #pragma unroll
        for (int tl = 0; tl < 50; ++tl) {
            float hv = hb[tl * 128 + tid];
            float y = fmaf(D, aq, CD * ap);
            aq = y;
            ap = fmaf(D, ap, hv);
            float q = fmaf(D, rq, CRD * rp);
            float u = y + q;
            float s = (u >= 1.0f) ? 1.0f : 0.0f;
            rq = q;
            rp = fmaf(D, rp, s);
            vbuf[tl * 129 + tid] = s * w2v;         // per-channel partial of o_t
        }
        __syncthreads();   // vbuf ready + next-chunk stage drained

        // ---- reduce o_t: wave0 lanes 0..49 sum ch 0..63; wave1 lanes sum ch 64..127
        if (tid < 50) {
            const float* row = &vbuf[tid * 129];
            float a0 = 0.f, a1 = 0.f, a2 = 0.f, a3 = 0.f;
            #pragma unroll
            for (int k = 0; k < 64; k += 4) {
                a0 += row[k]; a1 += row[k + 1]; a2 += row[k + 2]; a3 += row[k + 3];
            }
            pbuf[0][tid] = (a0 + a1) + (a2 + a3);
        } else if (tid >= 64 && tid < 114) {
            const float* row = &vbuf[(tid - 64) * 129 + 64];
            float a0 = 0.f, a1 = 0.f, a2 = 0.f, a3 = 0.f;
            #pragma unroll
            for (int k = 0; k < 64; k += 4) {
                a0 += row[k]; a1 += row[k + 1]; a2 += row[k + 2]; a3 += row[k + 3];
            }
            pbuf[1][tid - 64] = (a0 + a1) + (a2 + a3);
        }
        __syncthreads();

        // ---- layer-2: 50 serial steps, redundant on all lanes ----
        float my_s2 = 0.f;
        #pragma unroll
        for (int tl = 0; tl < 50; ++tl) {
            float ot = pbuf[0][tl] + pbuf[1][tl];
            float y2 = fmaf(D, Aq, CD * Ap);
            Aq = y2;
            Ap = fmaf(D, Ap, ot);
            float q2 = fmaf(D, Rq, CRD * Rp);
            float u2 = y2 + q2;
            float s2 = (u2 >= 1.0f) ? 1.0f : 0.0f;
            Rq = q2;
            Rp = fmaf(D, Rp, s2);
            if (tl == tid) my_s2 = s2;
        }
        if (tid < 50) out[(size_t)b * TT + chunk * 50 + tid] = my_s2;
        // no extra barrier needed: next scan writes vbuf only after the
        // post-reduce barrier; layer-2 reads only pbuf.
    }
}

// ---------------------------------------------------------------------------
extern "C" void kernel_launch(void* const* d_in, const int* in_sizes, int n_in,
                              void* d_out, int out_size, void* d_ws, size_t ws_size,
                              hipStream_t stream) {
    const float* x  = (const float*)d_in[0];   // (B, T, ENC) binary fp32
    const float* w1 = (const float*)d_in[1];   // (HID, ENC)
    const float* w2 = (const float*)d_in[2];   // (1, HID)
    float* out = (float*)d_out;                // (B, T, 1)

    float* h   = (float*)d_ws;                          // (T, B, HID) = 65.5 MB
    float* w1t = h + (size_t)TT * BB * HID;             // (ENC_PAD, HID)

    hipLaunchKernelGGL(transpose_w1_kernel, dim3(ENC_PAD), dim3(HID), 0, stream, w1, w1t);
    hipLaunchKernelGGL(spmm4_kernel, dim3((BB * TT) / 8), dim3(256), 0, stream, x, w1t, h);
    hipLaunchKernelGGL(recur_kernel, dim3(BB), dim3(128), 0, stream, h, w2, out);
}

// Round 2
// 593.682 us; speedup vs baseline: 1.0388x; 1.0137x over previous
//
#include <hip/hip_runtime.h>

#define BB  256
#define TT  500
#define ENC 700
#define ENC_PAD 704   // rows 700..703 of w1t are zeros (gather padding target)
#define HID 128

// ---------------------------------------------------------------------------
// Kernel 1: transpose w1 (HID, ENC) -> w1t (ENC_PAD, HID); pad rows = 0
// ---------------------------------------------------------------------------
__global__ __launch_bounds__(128) void transpose_w1_kernel(const float* __restrict__ w1,
                                                           float* __restrict__ w1t) {
    int c = blockIdx.x;      // 0..ENC_PAD-1
    int h = threadIdx.x;     // 0..HID-1
    w1t[c * HID + h] = (c < ENC) ? w1[h * ENC + c] : 0.0f;
}

// ---------------------------------------------------------------------------
// Kernel 2 (v4): compress + gather sparse binary GEMM, bit-exact sum order.
//   (unchanged this round — measured ~215 µs, bound by cache-line request
//   throughput of the 512 B-granular L2 gather, not by MLP; next structural
//   move is LDS-staged w1t, pending counter confirmation.)
// ---------------------------------------------------------------------------
__global__ __launch_bounds__(256, 4) void spmm4_kernel(const float* __restrict__ x,
                                                       const float* __restrict__ w1t,
                                                       float* __restrict__ h) {
    __shared__ ushort lists[8][152];                  // wave-private pairs of lists
    const int lane = threadIdx.x & 63;
    const int w = threadIdx.x >> 6;
    const int rbase = blockIdx.x * 8 + w * 2;         // rows rbase, rbase+1 (row = b*TT + t)
    const unsigned long long lt = (1ull << lane) - 1ull;

    // ---- phase 1: load both rows, all 22 dwords issued together ----
    const float* xrowA = x + (size_t)rbase * ENC;
    const float* xrowB = xrowA + ENC;
    float xva[11], xvb[11];
    #pragma unroll
    for (int k = 0; k < 11; ++k) {
        int c = k * 64 + lane;
        xva[k] = (c < ENC) ? xrowA[c] : 0.0f;
    }
    #pragma unroll
    for (int k = 0; k < 11; ++k) {
        int c = k * 64 + lane;
        xvb[k] = (c < ENC) ? xrowB[c] : 0.0f;
    }

    // ---- phase 2: ballot-compact into strictly ascending column lists ----
    int nA = 0, nB = 0;
    #pragma unroll
    for (int k = 0; k < 11; ++k) {
        bool act = (xva[k] != 0.0f);
        unsigned long long m = __ballot(act);
        if (act) {
            int pos = nA + (int)__popcll(m & lt);
            if (pos < 144) lists[2 * w + 0][pos] = (ushort)(k * 64 + lane);
        }
        nA += (int)__popcll(m);
    }
    #pragma unroll
    for (int k = 0; k < 11; ++k) {
        bool act = (xvb[k] != 0.0f);
        unsigned long long m = __ballot(act);
        if (act) {
            int pos = nB + (int)__popcll(m & lt);
            if (pos < 144) lists[2 * w + 1][pos] = (ushort)(k * 64 + lane);
        }
        nB += (int)__popcll(m);
    }
    nA = (nA < 144) ? nA : 144;
    nB = (nB < 144) ? nB : 144;
    int npmax = ((nA > nB ? nA : nB) + 3) & ~3;       // shared trip count, x4
    if (npmax < 4) npmax = 4;
    for (int p = nA + lane; p < npmax + 4; p += 64) lists[2 * w + 0][p] = (ushort)ENC;
    for (int p = nB + lane; p < npmax + 4; p += 64) lists[2 * w + 1][p] = (ushort)ENC;
    // lists are wave-private; in-wave LDS RAW ordered by lgkmcnt.

    // ---- phase 3: half-wave float4 gather, 2-stage pipeline ----
    const int half = lane >> 5;                       // 0 -> row A, 1 -> row B
    const int hl = lane & 31;                         // channel group: 4*hl..4*hl+3
    const ushort* mylist = lists[2 * w + half];
    const float* wb = w1t + 4 * hl;

    float a0 = 0.f, a1 = 0.f, a2 = 0.f, a3 = 0.f;

    int c0 = mylist[0], c1 = mylist[1], c2 = mylist[2], c3 = mylist[3];
    float4 p0 = *(const float4*)(wb + (size_t)c0 * HID);
    float4 p1 = *(const float4*)(wb + (size_t)c1 * HID);
    float4 p2 = *(const float4*)(wb + (size_t)c2 * HID);
    float4 p3 = *(const float4*)(wb + (size_t)c3 * HID);

    for (int j = 0; j < npmax; j += 4) {
        int d0 = mylist[j + 4], d1 = mylist[j + 5];
        int d2 = mylist[j + 6], d3 = mylist[j + 7];
        float4 q0 = *(const float4*)(wb + (size_t)d0 * HID);
        float4 q1 = *(const float4*)(wb + (size_t)d1 * HID);
        float4 q2 = *(const float4*)(wb + (size_t)d2 * HID);
        float4 q3 = *(const float4*)(wb + (size_t)d3 * HID);
        // ordered ascending-column accumulation; 4 independent channel chains
        a0 += p0.x; a1 += p0.y; a2 += p0.z; a3 += p0.w;
        a0 += p1.x; a1 += p1.y; a2 += p1.z; a3 += p1.w;
        a0 += p2.x; a1 += p2.y; a2 += p2.z; a3 += p2.w;
        a0 += p3.x; a1 += p3.y; a2 += p3.z; a3 += p3.w;
        p0 = q0; p1 = q1; p2 = q2; p3 = q3;
    }

    const int r = rbase + half;
    const int b = r / TT;
    const int t = r - b * TT;
    float4* dst = (float4*)(h + (size_t)t * (BB * HID) + (size_t)b * HID) + hl;
    *dst = make_float4(a0, a1, a2, a3);
}

// ---------------------------------------------------------------------------
// async global->LDS copy, 4 B per lane (wave-uniform LDS base + lane*4)
// ---------------------------------------------------------------------------
__device__ __forceinline__ void async_copy4(const float* g, float* l) {
    __builtin_amdgcn_global_load_lds(
        (const __attribute__((address_space(1))) void*)g,
        (__attribute__((address_space(3))) void*)l,
        4, 0, 0);
}

// ---------------------------------------------------------------------------
// Kernel 3 (v2): temporal pipeline per b. Block = 128 threads (2 waves).
//   At 0.5 waves/SIMD there is ZERO cross-wave latency hiding, so v1 was
//   LDS-latency-serialized: 50 sequential ds_read_b32 in the scan (~140 cyc
//   each), 100 sequential broadcast reads in layer-2, 4-deep reduce reads
//   -> ~17 µs/chunk. v2 batches every LDS-load phase into register arrays
//   (10-deep double-buffered scan, 64-wide reduce, 10-deep layer-2) so the
//   loads issue independently and amortize latency. All array indices are
//   compile-time constants (no scratch). Arithmetic sequence per accumulator
//   chain is IDENTICAL to v1 -> bit-exact output preserved.
// ---------------------------------------------------------------------------
__global__ __launch_bounds__(128) void recur_kernel(const float* __restrict__ hgl,
                                                    const float* __restrict__ w2,
                                                    float* __restrict__ out) {
    __shared__ float hbuf[2][50 * 128];   // 51.2 KB
    __shared__ float vbuf[50 * 129];      // 25.8 KB, stride 129 -> conflict-free rows
    __shared__ float pbuf[2][50];

    const int b = blockIdx.x;
    const int tid = threadIdx.x;          // 0..127
    const int lane = tid & 63;
    const int w = tid >> 6;

    const float D   = 0.95122942450071400910f;                                 // exp(-1/20)
    const float CD  = (float)(0.13591409142295226 * 0.95122942450071400910);   // (e/20)*d
    const float CRD = (float)(-0.27182818284590452 * 0.95122942450071400910);  // (-2e/20)*d

    float ap = 0.f, aq = 0.f, rp = 0.f, rq = 0.f;   // layer-1, channel = tid
    float Ap = 0.f, Aq = 0.f, Rp = 0.f, Rq = 0.f;   // layer-2, redundant on all lanes
    const float w2v = w2[tid];

    // stage chunk -> hbuf[buf]: wave w loads rows w*25..w*25+24, 2 halves each
    auto stage = [&](int chunk, int buf) {
        const int t0 = chunk * 50 + w * 25;
        #pragma unroll 5
        for (int i = 0; i < 25; ++i) {
            const float* g = hgl + (size_t)(t0 + i) * (BB * HID) + (size_t)b * HID + lane;
            float* l = &hbuf[buf][(w * 25 + i) * 128];
            async_copy4(g, l);
            async_copy4(g + 64, l + 64);
        }
    };

    stage(0, 0);
    __syncthreads();   // drains vmcnt -> chunk 0 resident

    for (int chunk = 0; chunk < 10; ++chunk) {
        const int cur = chunk & 1;
        if (chunk < 9) stage(chunk + 1, cur ^ 1);   // async, drained at next barrier

        // ---- layer-1 scan, 50 steps; h loads batched 10-deep, double-buffered
        const float* hb = &hbuf[cur][0];
        float hv[2][10];
        #pragma unroll
        for (int j = 0; j < 10; ++j) hv[0][j] = hb[j * 128 + tid];
        #pragma unroll
        for (int g = 0; g < 5; ++g) {
            const int cb = g & 1;
            if (g < 4) {
                #pragma unroll
                for (int j = 0; j < 10; ++j)
                    hv[cb ^ 1][j] = hb[((g + 1) * 10 + j) * 128 + tid];
            }
            #pragma unroll
            for (int j = 0; j < 10; ++j) {
                float h_ = hv[cb][j];
                float y = fmaf(D, aq, CD * ap);
                aq = y;
                ap = fmaf(D, ap, h_);
                float q = fmaf(D, rq, CRD * rp);
                float u = y + q;
                float s = (u >= 1.0f) ? 1.0f : 0.0f;
                rq = q;
                rp = fmaf(D, rp, s);
                vbuf[(g * 10 + j) * 129 + tid] = s * w2v;   // per-channel partial of o_t
            }
        }
        __syncthreads();   // vbuf ready + next-chunk stage drained

        // ---- reduce o_t: wave0 lanes 0..49 sum ch 0..63; wave1 ch 64..127.
        // All 64 loads issued up-front; add sequence identical to v1.
        if (tid < 50) {
            const float* row = &vbuf[tid * 129];
            float v[64];
            #pragma unroll
            for (int k = 0; k < 64; ++k) v[k] = row[k];
            float a0 = 0.f, a1 = 0.f, a2 = 0.f, a3 = 0.f;
            #pragma unroll
            for (int k = 0; k < 64; k += 4) {
                a0 += v[k]; a1 += v[k + 1]; a2 += v[k + 2]; a3 += v[k + 3];
            }
            pbuf[0][tid] = (a0 + a1) + (a2 + a3);
        } else if (tid >= 64 && tid < 114) {
            const float* row = &vbuf[(tid - 64) * 129 + 64];
            float v[64];
            #pragma unroll
            for (int k = 0; k < 64; ++k) v[k] = row[k];
            float a0 = 0.f, a1 = 0.f, a2 = 0.f, a3 = 0.f;
            #pragma unroll
            for (int k = 0; k < 64; k += 4) {
                a0 += v[k]; a1 += v[k + 1]; a2 += v[k + 2]; a3 += v[k + 3];
            }
            pbuf[1][tid - 64] = (a0 + a1) + (a2 + a3);
        }
        __syncthreads();

        // ---- layer-2: 50 serial steps; pbuf loads batched 10-deep, dbuf'd
        float my_s2 = 0.f;
        float p0v[2][10], p1v[2][10];
        #pragma unroll
        for (int j = 0; j < 10; ++j) {
            p0v[0][j] = pbuf[0][j];
            p1v[0][j] = pbuf[1][j];
        }
        #pragma unroll
        for (int g = 0; g < 5; ++g) {
            const int cb = g & 1;
            if (g < 4) {
                #pragma unroll
                for (int j = 0; j < 10; ++j) {
                    p0v[cb ^ 1][j] = pbuf[0][(g + 1) * 10 + j];
                    p1v[cb ^ 1][j] = pbuf[1][(g + 1) * 10 + j];
                }
            }
            #pragma unroll
            for (int j = 0; j < 10; ++j) {
                const int tl = g * 10 + j;
                float ot = p0v[cb][j] + p1v[cb][j];
                float y2 = fmaf(D, Aq, CD * Ap);
                Aq = y2;
                Ap = fmaf(D, Ap, ot);
                float q2 = fmaf(D, Rq, CRD * Rp);
                float u2 = y2 + q2;
                float s2 = (u2 >= 1.0f) ? 1.0f : 0.0f;
                Rq = q2;
                Rp = fmaf(D, Rp, s2);
                if (tl == tid) my_s2 = s2;
            }
        }
        if (tid < 50) out[(size_t)b * TT + chunk * 50 + tid] = my_s2;
        // no extra barrier needed: next scan writes vbuf only after the
        // post-reduce barrier; layer-2 reads only pbuf.
    }
}

// ---------------------------------------------------------------------------
extern "C" void kernel_launch(void* const* d_in, const int* in_sizes, int n_in,
                              void* d_out, int out_size, void* d_ws, size_t ws_size,
                              hipStream_t stream) {
    const float* x  = (const float*)d_in[0];   // (B, T, ENC) binary fp32
    const float* w1 = (const float*)d_in[1];   // (HID, ENC)
    const float* w2 = (const float*)d_in[2];   // (1, HID)
    float* out = (float*)d_out;                // (B, T, 1)

    float* h   = (float*)d_ws;                          // (T, B, HID) = 65.5 MB
    float* w1t = h + (size_t)TT * BB * HID;             // (ENC_PAD, HID)

    hipLaunchKernelGGL(transpose_w1_kernel, dim3(ENC_PAD), dim3(HID), 0, stream, w1, w1t);
    hipLaunchKernelGGL(spmm4_kernel, dim3((BB * TT) / 8), dim3(256), 0, stream, x, w1t, h);
    hipLaunchKernelGGL(recur_kernel, dim3(BB), dim3(128), 0, stream, h, w2, out);
}

// Round 3
// 590.439 us; speedup vs baseline: 1.0445x; 1.0055x over previous
//
#include <hip/hip_runtime.h>

#define BB  256
#define TT  500
#define ENC 700
#define ENC_PAD 704   // rows 700..703 of w1t are zeros (gather padding target)
#define HID 128

// ---------------------------------------------------------------------------
// Kernel 1: transpose w1 (HID, ENC) -> w1t (ENC_PAD, HID); pad rows = 0
// ---------------------------------------------------------------------------
__global__ __launch_bounds__(128) void transpose_w1_kernel(const float* __restrict__ w1,
                                                           float* __restrict__ w1t) {
    int c = blockIdx.x;      // 0..ENC_PAD-1
    int h = threadIdx.x;     // 0..HID-1
    w1t[c * HID + h] = (c < ENC) ? w1[h * ENC + c] : 0.0f;
}

// ---------------------------------------------------------------------------
// Kernel 2 (v4b): compress + gather sparse binary GEMM, bit-exact sum order.
//   Same as v4 except h is now laid out [b][t][ch] = h[r*HID] (r = b*TT+t):
//   the two half-wave row outputs become one contiguous 1 KB store per wave
//   instead of two scattered 512 B stores. Gather path unchanged (~TA-bound;
//   the LDS-staged-w1t rewrite is the next structural move if needed).
// ---------------------------------------------------------------------------
__global__ __launch_bounds__(256, 4) void spmm4_kernel(const float* __restrict__ x,
                                                       const float* __restrict__ w1t,
                                                       float* __restrict__ h) {
    __shared__ ushort lists[8][152];                  // wave-private pairs of lists
    const int lane = threadIdx.x & 63;
    const int w = threadIdx.x >> 6;
    const int rbase = blockIdx.x * 8 + w * 2;         // rows rbase, rbase+1 (row = b*TT + t)
    const unsigned long long lt = (1ull << lane) - 1ull;

    // ---- phase 1: load both rows, all 22 dwords issued together ----
    const float* xrowA = x + (size_t)rbase * ENC;
    const float* xrowB = xrowA + ENC;
    float xva[11], xvb[11];
    #pragma unroll
    for (int k = 0; k < 11; ++k) {
        int c = k * 64 + lane;
        xva[k] = (c < ENC) ? xrowA[c] : 0.0f;
    }
    #pragma unroll
    for (int k = 0; k < 11; ++k) {
        int c = k * 64 + lane;
        xvb[k] = (c < ENC) ? xrowB[c] : 0.0f;
    }

    // ---- phase 2: ballot-compact into strictly ascending column lists ----
    int nA = 0, nB = 0;
    #pragma unroll
    for (int k = 0; k < 11; ++k) {
        bool act = (xva[k] != 0.0f);
        unsigned long long m = __ballot(act);
        if (act) {
            int pos = nA + (int)__popcll(m & lt);
            if (pos < 144) lists[2 * w + 0][pos] = (ushort)(k * 64 + lane);
        }
        nA += (int)__popcll(m);
    }
    #pragma unroll
    for (int k = 0; k < 11; ++k) {
        bool act = (xvb[k] != 0.0f);
        unsigned long long m = __ballot(act);
        if (act) {
            int pos = nB + (int)__popcll(m & lt);
            if (pos < 144) lists[2 * w + 1][pos] = (ushort)(k * 64 + lane);
        }
        nB += (int)__popcll(m);
    }
    nA = (nA < 144) ? nA : 144;
    nB = (nB < 144) ? nB : 144;
    int npmax = ((nA > nB ? nA : nB) + 3) & ~3;       // shared trip count, x4
    if (npmax < 4) npmax = 4;
    for (int p = nA + lane; p < npmax + 4; p += 64) lists[2 * w + 0][p] = (ushort)ENC;
    for (int p = nB + lane; p < npmax + 4; p += 64) lists[2 * w + 1][p] = (ushort)ENC;
    // lists are wave-private; in-wave LDS RAW ordered by lgkmcnt.

    // ---- phase 3: half-wave float4 gather, 2-stage pipeline ----
    const int half = lane >> 5;                       // 0 -> row A, 1 -> row B
    const int hl = lane & 31;                         // channel group: 4*hl..4*hl+3
    const ushort* mylist = lists[2 * w + half];
    const float* wb = w1t + 4 * hl;

    float a0 = 0.f, a1 = 0.f, a2 = 0.f, a3 = 0.f;

    int c0 = mylist[0], c1 = mylist[1], c2 = mylist[2], c3 = mylist[3];
    float4 p0 = *(const float4*)(wb + (size_t)c0 * HID);
    float4 p1 = *(const float4*)(wb + (size_t)c1 * HID);
    float4 p2 = *(const float4*)(wb + (size_t)c2 * HID);
    float4 p3 = *(const float4*)(wb + (size_t)c3 * HID);

    for (int j = 0; j < npmax; j += 4) {
        int d0 = mylist[j + 4], d1 = mylist[j + 5];
        int d2 = mylist[j + 6], d3 = mylist[j + 7];
        float4 q0 = *(const float4*)(wb + (size_t)d0 * HID);
        float4 q1 = *(const float4*)(wb + (size_t)d1 * HID);
        float4 q2 = *(const float4*)(wb + (size_t)d2 * HID);
        float4 q3 = *(const float4*)(wb + (size_t)d3 * HID);
        // ordered ascending-column accumulation; 4 independent channel chains
        a0 += p0.x; a1 += p0.y; a2 += p0.z; a3 += p0.w;
        a0 += p1.x; a1 += p1.y; a2 += p1.z; a3 += p1.w;
        a0 += p2.x; a1 += p2.y; a2 += p2.z; a3 += p2.w;
        a0 += p3.x; a1 += p3.y; a2 += p3.z; a3 += p3.w;
        p0 = q0; p1 = q1; p2 = q2; p3 = q3;
    }

    // h layout [b][t][ch]: row r is contiguous at h + r*HID
    const int r = rbase + half;
    float4* dst = (float4*)(h + (size_t)r * HID) + hl;
    *dst = make_float4(a0, a1, a2, a3);
}

// ---------------------------------------------------------------------------
// Kernel 3 (v3): temporal pipeline per b. Block = 128 threads (2 waves),
// 1 channel/lane.
//   v1/v2 spent ~16 µs/chunk somewhere in the h-staging path (serial chains
//   + reduce model out at ~1.5 µs/chunk). v3 removes both staging suspects:
//   (a) h is now [b][t][ch] -> each block reads a PRIVATE CONTIGUOUS stream
//       (25.6 KB/chunk sequential) instead of 512 B scattered at 128 KB
//       stride across drifting blocks (DRAM row-miss-dominated);
//   (b) global_load_lds + hbuf dropped -> h prefetched straight into named
//       register arrays hA/hB (50-deep, double-buffered, all indices
//       compile-time constants), one chunk ahead.
//   vbuf/pbuf reduce and layer-2 keep the exact v1 arithmetic sequence ->
//   bit-exact output preserved.
// ---------------------------------------------------------------------------
__global__ __launch_bounds__(128) void recur_kernel(const float* __restrict__ hgl,
                                                    const float* __restrict__ w2,
                                                    float* __restrict__ out) {
    __shared__ float vbuf[50 * 129];      // 25.8 KB, stride 129 -> conflict-free rows
    __shared__ float pbuf[2][50];

    const int b = blockIdx.x;
    const int tid = threadIdx.x;          // 0..127

    const float D   = 0.95122942450071400910f;                                 // exp(-1/20)
    const float CD  = (float)(0.13591409142295226 * 0.95122942450071400910);   // (e/20)*d
    const float CRD = (float)(-0.27182818284590452 * 0.95122942450071400910);  // (-2e/20)*d

    float ap = 0.f, aq = 0.f, rp = 0.f, rq = 0.f;   // layer-1, channel = tid
    float Ap = 0.f, Aq = 0.f, Rp = 0.f, Rq = 0.f;   // layer-2, redundant on all lanes
    const float w2v = w2[tid];

    // h[b][t][ch]: this block's h is one contiguous 256 KB stream
    const float* hb = hgl + (size_t)b * (TT * HID) + tid;

    float hA[50], hB[50];

    // one chunk = 50 t-steps: scan -> reduce -> layer-2 (arithmetic == v1)
    auto body = [&](const float (&hv)[50], int chunk) {
        // ---- layer-1 scan, 50 steps, h from registers ----
        #pragma unroll
        for (int tl = 0; tl < 50; ++tl) {
            float h_ = hv[tl];
            float y = fmaf(D, aq, CD * ap);
            aq = y;
            ap = fmaf(D, ap, h_);
            float q = fmaf(D, rq, CRD * rp);
            float u = y + q;
            float s = (u >= 1.0f) ? 1.0f : 0.0f;
            rq = q;
            rp = fmaf(D, rp, s);
            vbuf[tl * 129 + tid] = s * w2v;         // per-channel partial of o_t
        }
        __syncthreads();   // vbuf ready (also completes in-flight prefetch)

        // ---- reduce o_t: wave0 lanes 0..49 sum ch 0..63; wave1 ch 64..127
        if (tid < 50) {
            const float* row = &vbuf[tid * 129];
            float a0 = 0.f, a1 = 0.f, a2 = 0.f, a3 = 0.f;
            #pragma unroll
            for (int k = 0; k < 64; k += 4) {
                a0 += row[k]; a1 += row[k + 1]; a2 += row[k + 2]; a3 += row[k + 3];
            }
            pbuf[0][tid] = (a0 + a1) + (a2 + a3);
        } else if (tid >= 64 && tid < 114) {
            const float* row = &vbuf[(tid - 64) * 129 + 64];
            float a0 = 0.f, a1 = 0.f, a2 = 0.f, a3 = 0.f;
            #pragma unroll
            for (int k = 0; k < 64; k += 4) {
                a0 += row[k]; a1 += row[k + 1]; a2 += row[k + 2]; a3 += row[k + 3];
            }
            pbuf[1][tid - 64] = (a0 + a1) + (a2 + a3);
        }
        __syncthreads();

        // ---- layer-2: 50 serial steps, redundant on all lanes ----
        float my_s2 = 0.f;
        #pragma unroll
        for (int tl = 0; tl < 50; ++tl) {
            float ot = pbuf[0][tl] + pbuf[1][tl];
            float y2 = fmaf(D, Aq, CD * Ap);
            Aq = y2;
            Ap = fmaf(D, Ap, ot);
            float q2 = fmaf(D, Rq, CRD * Rp);
            float u2 = y2 + q2;
            float s2 = (u2 >= 1.0f) ? 1.0f : 0.0f;
            Rq = q2;
            Rp = fmaf(D, Rp, s2);
            if (tl == tid) my_s2 = s2;
        }
        if (tid < 50) out[(size_t)b * TT + chunk * 50 + tid] = my_s2;
        // no trailing barrier needed: next scan's vbuf writes are safe because
        // a lagging thread still in layer-2 hasn't passed the next body's
        // first barrier, which precedes any pbuf overwrite.
    };

    // prologue: chunk 0 into hA
    #pragma unroll
    for (int j = 0; j < 50; ++j) hA[j] = hb[j * HID];

    for (int cp = 0; cp < 5; ++cp) {
        // prefetch odd chunk into hB, then consume hA
        {
            const float* g = hb + (size_t)(2 * cp + 1) * 50 * HID;
            #pragma unroll
            for (int j = 0; j < 50; ++j) hB[j] = g[j * HID];
        }
        body(hA, 2 * cp);
        // prefetch next even chunk into hA, then consume hB
        if (cp < 4) {
            const float* g = hb + (size_t)(2 * cp + 2) * 50 * HID;
            #pragma unroll
            for (int j = 0; j < 50; ++j) hA[j] = g[j * HID];
        }
        body(hB, 2 * cp + 1);
    }
}

// ---------------------------------------------------------------------------
extern "C" void kernel_launch(void* const* d_in, const int* in_sizes, int n_in,
                              void* d_out, int out_size, void* d_ws, size_t ws_size,
                              hipStream_t stream) {
    const float* x  = (const float*)d_in[0];   // (B, T, ENC) binary fp32
    const float* w1 = (const float*)d_in[1];   // (HID, ENC)
    const float* w2 = (const float*)d_in[2];   // (1, HID)
    float* out = (float*)d_out;                // (B, T, 1)

    float* h   = (float*)d_ws;                          // (B, T, HID) = 65.5 MB
    float* w1t = h + (size_t)TT * BB * HID;             // (ENC_PAD, HID)

    hipLaunchKernelGGL(transpose_w1_kernel, dim3(ENC_PAD), dim3(HID), 0, stream, w1, w1t);
    hipLaunchKernelGGL(spmm4_kernel, dim3((BB * TT) / 8), dim3(256), 0, stream, x, w1t, h);
    hipLaunchKernelGGL(recur_kernel, dim3(BB), dim3(128), 0, stream, h, w2, out);
}